// Round 15
// baseline (379.097 us; speedup 1.0000x reference)
//
#include <hip/hip_runtime.h>
#include <math.h>

// ---- problem constants ----
constexpr int BB   = 1024;   // batch
constexpr int NN   = 2048;   // memory slots
constexpr int DD   = 64;     // memory width
constexpr int RR   = 4;      // read heads
constexpr float GAMMA = 0.95f;

// ---- d_out flat layout (float elements, reference return order) ----
constexpr size_t OUT_OUT = 0;                                   // (B, 768)
constexpr size_t OUT_MT  = OUT_OUT + (size_t)BB * 768;          // (B, N, D)
constexpr size_t OUT_RT  = OUT_MT  + (size_t)BB * NN * DD;      // (B, 256)
constexpr size_t OUT_HT  = OUT_RT  + (size_t)BB * 256;          // (B, 512)
constexpr size_t OUT_CT  = OUT_HT  + (size_t)BB * 512;          // (B, 512)
constexpr size_t OUT_WU  = OUT_CT  + (size_t)BB * 512;          // (B, N)
constexpr size_t OUT_WR  = OUT_WU  + (size_t)BB * NN;           // (B, R*N)

// ---- scratch inside M_t region, per-batch slice (header read before overwrite) ----
constexpr int SLICE   = NN * DD;       // 131072
constexpr int OFF_G   = 8456 + NN;     // gates: 2048
constexpr int OFF_P   = OFF_G + 2048;  // p: 520   (rows 196..204 of M_t; read before loop)

// bf16 operand stashes (dead scratch until overwritten by later kernels):
//   A_bf16   [1024][1024]  (2 MB)   at out+OUT_WU
//   Wlin_bf16 [576][512]  (288 KB)  at out+OUT_WU + 4 MB
//   W_bf16   [2048][1024]  (4 MB)   at out+OUT_WR
//   h_bf16   [1024][512]   (1 MB)   at out+OUT_RT (overwritten by fused_mem r_t)

__device__ __forceinline__ float sigmoidf_(float x) { return 1.0f / (1.0f + __expf(-x)); }

typedef short short8 __attribute__((ext_vector_type(8)));
typedef float f32x4  __attribute__((ext_vector_type(4)));

// pack two f32 into one dword of 2 bf16 (round-to-nearest-even)
__device__ __forceinline__ unsigned bf16pack2(float a, float b) {
    unsigned ua = __float_as_uint(a), ub = __float_as_uint(b);
    ua = (ua + 0x7FFFu + ((ua >> 16) & 1u)) >> 16;
    ub = (ub + 0x7FFFu + ((ub >> 16) & 1u)) >> 16;
    return ua | (ub << 16);
}

// VALU-pipe cross-lane add within each 16-lane row: x + dpp(x).
template<int CTRL>
__device__ __forceinline__ float dpp_add(float x) {
    int y = __builtin_amdgcn_update_dpp(0, __float_as_int(x), CTRL, 0xF, 0xF, false);
    return x + __int_as_float(y);
}
template<int CTRL>
__device__ __forceinline__ void dpp_add5(float& a, float& b, float& c, float& d, float& e) {
    a = dpp_add<CTRL>(a); b = dpp_add<CTRL>(b); c = dpp_add<CTRL>(c);
    d = dpp_add<CTRL>(d); e = dpp_add<CTRL>(e);
}
// quad_perm broadcast of lane (base of quad + L) to all 4 lanes of the quad
template<int CTRL>
__device__ __forceinline__ float dpp_bcast(float x) {
    return __int_as_float(__builtin_amdgcn_update_dpp(0, __float_as_int(x), CTRL, 0xF, 0xF, false));
}

// ===================== conv_all: f32 -> bf16 stashes (A, W, Wlin) =====================
__global__ __launch_bounds__(256) void conv_all(
    const float* __restrict__ x, const float* __restrict__ rprev, const float* __restrict__ hprev,
    const float* __restrict__ Wih, const float* __restrict__ Whh, const float* __restrict__ Wlin,
    unsigned* __restrict__ Abf, unsigned* __restrict__ Wbf, unsigned* __restrict__ Wlbf)
{
    const int bid = blockIdx.x;
    if (bid < 512) {
        const int gid = bid * 256 + threadIdx.x;
        const int e0 = gid * 8;
        const int row = e0 >> 10, col = e0 & 1023;
        float4 v0, v1;
        if (col < 256)      { const float* p = x + row * 256 + col;
                              v0 = *(const float4*)p; v1 = *(const float4*)(p + 4); }
        else if (col < 512) { const float* p = rprev + row * 256 + (col - 256);
                              v0 = *(const float4*)p; v1 = *(const float4*)(p + 4); }
        else                { const float* p = hprev + row * 512 + (col - 512);
                              v0 = *(const float4*)p; v1 = *(const float4*)(p + 4); }
        uint4 o;
        o.x = bf16pack2(v0.x, v0.y); o.y = bf16pack2(v0.z, v0.w);
        o.z = bf16pack2(v1.x, v1.y); o.w = bf16pack2(v1.z, v1.w);
        *(uint4*)(Abf + (size_t)row * 512 + (col >> 1)) = o;
    } else if (bid < 1536) {
        const int gid = (bid - 512) * 256 + threadIdx.x;
        const int e0 = gid * 8;
        const int row = e0 >> 10, col = e0 & 1023;
        float4 v0, v1;
        if (col < 512) { const float* p = Wih + (size_t)row * 512 + col;
                         v0 = *(const float4*)p; v1 = *(const float4*)(p + 4); }
        else           { const float* p = Whh + (size_t)row * 512 + (col - 512);
                         v0 = *(const float4*)p; v1 = *(const float4*)(p + 4); }
        uint4 o;
        o.x = bf16pack2(v0.x, v0.y); o.y = bf16pack2(v0.z, v0.w);
        o.z = bf16pack2(v1.x, v1.y); o.w = bf16pack2(v1.z, v1.w);
        *(uint4*)(Wbf + (size_t)row * 512 + (col >> 1)) = o;
    } else {
        const int gid = (bid - 1536) * 256 + threadIdx.x;
        const int e0 = gid * 8;
        const int row = e0 >> 9, col = e0 & 511;
        const float* p = Wlin + (size_t)row * 512 + col;
        const float4 v0 = *(const float4*)p, v1 = *(const float4*)(p + 4);
        uint4 o;
        o.x = bf16pack2(v0.x, v0.y); o.y = bf16pack2(v0.z, v0.w);
        o.z = bf16pack2(v1.x, v1.y); o.w = bf16pack2(v1.z, v1.w);
        *(uint4*)(Wlbf + (size_t)row * 256 + (col >> 1)) = o;
    }
}

// ===================== GEMM 1 (bf16 MFMA): gates = A @ W^T + b =====================
__global__ __launch_bounds__(256) void gemm_gates(
    const unsigned* __restrict__ Abf, const unsigned* __restrict__ Wbf,
    const float* __restrict__ bih, const float* __restrict__ bhh,
    float* __restrict__ out)
{
    __shared__ unsigned As[64][20];   // 64 rows x 40 bf16 (32 data + 8 pad)
    __shared__ unsigned Bs[64][20];
    const int t = threadIdx.x;
    const int wave = t >> 6, lane = t & 63;
    const int row0 = blockIdx.y * 64, col0 = blockIdx.x * 64;
    const int srow = t >> 2;
    const int sk4  = (t & 3) * 4;
    const int wm = wave >> 1, wn = wave & 1;
    const int lrow = lane & 15;
    const int ldw  = (lane >> 4) * 4;

    f32x4 acc00 = {0.f,0.f,0.f,0.f}, acc01 = {0.f,0.f,0.f,0.f};
    f32x4 acc10 = {0.f,0.f,0.f,0.f}, acc11 = {0.f,0.f,0.f,0.f};

    for (int k0 = 0; k0 < 512; k0 += 16) {   // u32 units: 32 bf16 per step
        const uint4 av = *(const uint4*)(Abf + (size_t)(row0 + srow) * 512 + k0 + sk4);
        const uint4 bv = *(const uint4*)(Wbf + (size_t)(col0 + srow) * 512 + k0 + sk4);
        __syncthreads();
        *(uint4*)&As[srow][sk4] = av;
        *(uint4*)&Bs[srow][sk4] = bv;
        __syncthreads();
        const short8 a0 = *(const short8*)&As[32 * wm + lrow][ldw];
        const short8 a1 = *(const short8*)&As[32 * wm + 16 + lrow][ldw];
        const short8 b0 = *(const short8*)&Bs[32 * wn + lrow][ldw];
        const short8 b1 = *(const short8*)&Bs[32 * wn + 16 + lrow][ldw];
        acc00 = __builtin_amdgcn_mfma_f32_16x16x32_bf16(a0, b0, acc00, 0, 0, 0);
        acc01 = __builtin_amdgcn_mfma_f32_16x16x32_bf16(a0, b1, acc01, 0, 0, 0);
        acc10 = __builtin_amdgcn_mfma_f32_16x16x32_bf16(a1, b0, acc10, 0, 0, 0);
        acc11 = __builtin_amdgcn_mfma_f32_16x16x32_bf16(a1, b1, acc11, 0, 0, 0);
    }

    float* mt = out + OUT_MT;
    const int rbase = row0 + 32 * wm + (lane >> 4) * 4;
    #pragma unroll
    for (int ni = 0; ni < 2; ni++) {
        const int col = col0 + 32 * wn + 16 * ni + lrow;
        const float bb = bih[col] + bhh[col];
        #pragma unroll
        for (int reg = 0; reg < 4; reg++) {
            const float v0 = (ni == 0) ? acc00[reg] : acc01[reg];
            const float v1 = (ni == 0) ? acc10[reg] : acc11[reg];
            mt[(size_t)(rbase + reg) * SLICE + OFF_G + col] = v0 + bb;
            mt[(size_t)(rbase + 16 + reg) * SLICE + OFF_G + col] = v1 + bb;
        }
    }
}

// ===================== LSTM pointwise (float4) + h bf16 stash =====================
__global__ __launch_bounds__(256) void lstm_pw(const float* __restrict__ cprev, float* __restrict__ out)
{
    const size_t e0 = ((size_t)blockIdx.x * 256 + threadIdx.x) * 4;  // 0 .. B*512-4
    const int b = (int)(e0 >> 9), j = (int)(e0 & 511);
    const float* g = out + OUT_MT + (size_t)b * SLICE + OFF_G;
    const float4 ig = *(const float4*)(g + j);
    const float4 fg = *(const float4*)(g + 512 + j);
    const float4 gg = *(const float4*)(g + 1024 + j);
    const float4 og = *(const float4*)(g + 1536 + j);
    const float4 cp = *(const float4*)(cprev + e0);
    float4 c, h;
    c.x = sigmoidf_(fg.x) * cp.x + sigmoidf_(ig.x) * tanhf(gg.x);
    c.y = sigmoidf_(fg.y) * cp.y + sigmoidf_(ig.y) * tanhf(gg.y);
    c.z = sigmoidf_(fg.z) * cp.z + sigmoidf_(ig.z) * tanhf(gg.z);
    c.w = sigmoidf_(fg.w) * cp.w + sigmoidf_(ig.w) * tanhf(gg.w);
    h.x = sigmoidf_(og.x) * tanhf(c.x);
    h.y = sigmoidf_(og.y) * tanhf(c.y);
    h.z = sigmoidf_(og.z) * tanhf(c.z);
    h.w = sigmoidf_(og.w) * tanhf(c.w);
    *(float4*)(out + OUT_CT + e0) = c;
    *(float4*)(out + OUT_HT + e0) = h;
    *(float4*)(out + (size_t)b * 768 + j) = h;
    unsigned* hbf = (unsigned*)(out + OUT_RT);
    uint2 hp; hp.x = bf16pack2(h.x, h.y); hp.y = bf16pack2(h.z, h.w);
    *(uint2*)(hbf + (size_t)b * 256 + (j >> 1)) = hp;
}

// ===================== GEMM 2 (bf16 MFMA): p = h @ Wlin^T + b_lin =====================
__global__ __launch_bounds__(256) void gemm_p(
    const unsigned* __restrict__ Hbf, const unsigned* __restrict__ Wlbf,
    const float* __restrict__ blin, float* __restrict__ out)
{
    __shared__ unsigned As[64][20];
    __shared__ unsigned Bs[64][20];
    const int t = threadIdx.x;
    const int wave = t >> 6, lane = t & 63;
    const int row0 = blockIdx.y * 64, col0 = blockIdx.x * 64;
    const int srow = t >> 2;
    const int sk4  = (t & 3) * 4;
    const int wm = wave >> 1, wn = wave & 1;
    const int lrow = lane & 15;
    const int ldw  = (lane >> 4) * 4;

    f32x4 acc00 = {0.f,0.f,0.f,0.f}, acc01 = {0.f,0.f,0.f,0.f};
    f32x4 acc10 = {0.f,0.f,0.f,0.f}, acc11 = {0.f,0.f,0.f,0.f};

    for (int k0 = 0; k0 < 256; k0 += 16) {   // u32 units: K=512 bf16
        const uint4 av = *(const uint4*)(Hbf  + (size_t)(row0 + srow) * 256 + k0 + sk4);
        const uint4 bv = *(const uint4*)(Wlbf + (size_t)(col0 + srow) * 256 + k0 + sk4);
        __syncthreads();
        *(uint4*)&As[srow][sk4] = av;
        *(uint4*)&Bs[srow][sk4] = bv;
        __syncthreads();
        const short8 a0 = *(const short8*)&As[32 * wm + lrow][ldw];
        const short8 a1 = *(const short8*)&As[32 * wm + 16 + lrow][ldw];
        const short8 b0 = *(const short8*)&Bs[32 * wn + lrow][ldw];
        const short8 b1 = *(const short8*)&Bs[32 * wn + 16 + lrow][ldw];
        acc00 = __builtin_amdgcn_mfma_f32_16x16x32_bf16(a0, b0, acc00, 0, 0, 0);
        acc01 = __builtin_amdgcn_mfma_f32_16x16x32_bf16(a0, b1, acc01, 0, 0, 0);
        acc10 = __builtin_amdgcn_mfma_f32_16x16x32_bf16(a1, b0, acc10, 0, 0, 0);
        acc11 = __builtin_amdgcn_mfma_f32_16x16x32_bf16(a1, b1, acc11, 0, 0, 0);
    }

    float* mt = out + OUT_MT;
    const int rbase = row0 + 32 * wm + (lane >> 4) * 4;
    #pragma unroll
    for (int ni = 0; ni < 2; ni++) {
        const int col = col0 + 32 * wn + 16 * ni + lrow;
        if (col < 516) {
            const float bb = blin[col];
            #pragma unroll
            for (int reg = 0; reg < 4; reg++) {
                const float v0 = (ni == 0) ? acc00[reg] : acc01[reg];
                const float v1 = (ni == 0) ? acc10[reg] : acc11[reg];
                mt[(size_t)(rbase + reg) * SLICE + OFF_P + col] = v0 + bb;
                mt[(size_t)(rbase + 16 + reg) * SLICE + OFF_P + col] = v1 + bb;
            }
        }
    }
}

// ===================== FUSED: header (k/a/sa/rck/argmin) + memory pass + softmax ==========
// One block per batch (512 thr = 8 waves). Single M_prev read, single M_t write.
// Row mapping: group g = wave*4+row4 owns rows [g*64, g*64+64) -> contiguous m4/wrp access.
// Exp dedup: lane q=lane&3 computes exp for head q; quad_perm broadcasts e0..e3.
__global__ __launch_bounds__(512) void fused_mem(
    const float* __restrict__ Mprev, const float* __restrict__ wrprev,
    const float* __restrict__ wuprev, float* __restrict__ out)
{
    const int b = blockIdx.x, t = threadIdx.x;
    const int wave = t >> 6, lane = t & 63;
    const int row4 = lane >> 4, d4 = lane & 15;
    float* mt = out + OUT_MT;
    const size_t sl = (size_t)b * SLICE;

    __shared__ float4 s_e4[NN];     // 32 KB: e[n][r]; reused as lr in final merge
    __shared__ float  lz[8][4];
    __shared__ float  s_k[256], s_a[256];
    __shared__ float  s_sa[4], s_rck[4];
    __shared__ float  wvred[8];
    __shared__ int    wired[8];
    __shared__ int    chosen[4];

    // ---- header part 1: k, a, sigma(alpha), 1/||k|| from p (waves 0-3) ----
    {
        const float* p = mt + sl + OFF_P;
        if (t < 256) {
            const int r = t >> 6, d = t & 63;
            const float kv = tanhf(p[r * 64 + d]);
            const float av = tanhf(p[256 + r * 64 + d]);
            s_k[t] = kv; s_a[t] = av;
            float s2 = kv * kv;
            #pragma unroll
            for (int off = 1; off < 64; off <<= 1) s2 += __shfl_xor(s2, off);
            if (d == 0) s_rck[r] = rsqrtf(s2);
            if (t < 4) s_sa[t] = sigmoidf_(p[512 + t]);
        }
    }

    // ---- header part 2: 4 smallest wu_prev indices (tie -> larger index) ----
    {
        float wu4[4];
        #pragma unroll
        for (int i = 0; i < 4; i++) wu4[i] = wuprev[(size_t)b * NN + t + i * 512];
        for (int it = 0; it < 4; it++) {
            float bv = 3.4e38f; int bi = -1;
            #pragma unroll
            for (int i = 0; i < 4; i++) {
                const int n = t + i * 512;
                bool skip = false;
                for (int j = 0; j < it; j++) skip = skip || (n == chosen[j]);
                const float v = wu4[i];
                if (!skip && (v < bv || (v == bv && n > bi))) { bv = v; bi = n; }
            }
            #pragma unroll
            for (int off = 1; off < 64; off <<= 1) {
                const float v2 = __shfl_xor(bv, off);
                const int   i2 = __shfl_xor(bi, off);
                if (v2 < bv || (v2 == bv && i2 > bi)) { bv = v2; bi = i2; }
            }
            if (lane == 0) { wvred[wave] = bv; wired[wave] = bi; }
            __syncthreads();
            if (t == 0) {
                float fv = wvred[0]; int fi = wired[0];
                #pragma unroll
                for (int w = 1; w < 8; w++) {
                    if (wvred[w] < fv || (wvred[w] == fv && wired[w] > fi)) { fv = wvred[w]; fi = wired[w]; }
                }
                chosen[it] = fi;
            }
            __syncthreads();
        }
    }

    // ---- gather header results ----
    float sa[4], rck[4]; int id4[4];
    float4 k4[4], a4[4];
    #pragma unroll
    for (int r = 0; r < 4; r++) {
        sa[r]  = s_sa[r];
        rck[r] = s_rck[r];
        id4[r] = chosen[r];
        k4[r] = *(const float4*)&s_k[r * 64 + d4 * 4];
        a4[r] = *(const float4*)&s_a[r * 64 + d4 * 4];
    }
    // per-lane rck for the dedup'd exp (static selects, no dynamic indexing)
    const float rck_lane = (lane & 2) ? ((lane & 1) ? rck[3] : rck[2])
                                      : ((lane & 1) ? rck[1] : rck[0]);

    const float* wrp = wrprev + (size_t)b * (RR * NN);
    const int kill = id4[0];
    const int g = wave * 4 + row4;                     // row group: owns rows [g*64, g*64+64)
    const size_t gbase = (size_t)b * NN * DD + (size_t)(g * 64) * DD + (size_t)(d4 * 4);

    float4 racc[4];
    #pragma unroll
    for (int r = 0; r < 4; r++) racc[r] = make_float4(0.f, 0.f, 0.f, 0.f);

    // prologue: load first row of the group
    float4 m4 = *(const float4*)(Mprev + gbase);

    for (int it = 0; it < 64; it++) {
        const int n = g * 64 + it;
        const int itn = (it + 1) & 63;                 // wrap: last-iter prefetch reloads row 0 (unused)
        const float4 m4n = *(const float4*)(Mprev + gbase + (size_t)itn * DD);
        const float w0 = wrp[0 * NN + n];
        const float w1 = wrp[1 * NN + n];
        const float w2 = wrp[2 * NN + n];
        const float w3 = wrp[3 * NN + n];

        float nrm = m4.x * m4.x + m4.y * m4.y + m4.z * m4.z + m4.w * m4.w;
        float ip0 = k4[0].x * m4.x + k4[0].y * m4.y + k4[0].z * m4.z + k4[0].w * m4.w;
        float ip1 = k4[1].x * m4.x + k4[1].y * m4.y + k4[1].z * m4.z + k4[1].w * m4.w;
        float ip2 = k4[2].x * m4.x + k4[2].y * m4.y + k4[2].z * m4.z + k4[2].w * m4.w;
        float ip3 = k4[3].x * m4.x + k4[3].y * m4.y + k4[3].z * m4.z + k4[3].w * m4.w;
        dpp_add5<0xB1>(nrm, ip0, ip1, ip2, ip3);   // quad_perm xor1
        dpp_add5<0x4E>(nrm, ip0, ip1, ip2, ip3);   // quad_perm xor2
        dpp_add5<0x124>(nrm, ip0, ip1, ip2, ip3);  // row_ror:4
        dpp_add5<0x128>(nrm, ip0, ip1, ip2, ip3);  // row_ror:8

        const float rsn = rsqrtf(fmaxf(nrm, 1e-30f));
        // exp dedup: lane q computes head q's exp; quad_perm broadcasts all 4
        const float ipsel = (lane & 2) ? ((lane & 1) ? ip3 : ip2)
                                       : ((lane & 1) ? ip1 : ip0);
        const float esel = __expf(ipsel * rck_lane * rsn);
        const float e0 = dpp_bcast<0x00>(esel);
        const float e1 = dpp_bcast<0x55>(esel);
        const float e2 = dpp_bcast<0xAA>(esel);
        const float e3 = dpp_bcast<0xFF>(esel);
        if (d4 == 0) s_e4[n] = make_float4(e0, e1, e2, e3);

        const float wlu = (n == id4[0] || n == id4[1] || n == id4[2] || n == id4[3]) ? 1.0f : 0.0f;
        float4 mtv = m4;
        if (n == kill) { mtv.x = 0.f; mtv.y = 0.f; mtv.z = 0.f; mtv.w = 0.f; }
        const float ww0 = fmaf(sa[0], w0 - wlu, wlu);
        const float ww1 = fmaf(sa[1], w1 - wlu, wlu);
        const float ww2 = fmaf(sa[2], w2 - wlu, wlu);
        const float ww3 = fmaf(sa[3], w3 - wlu, wlu);
        mtv.x += ww0 * a4[0].x + ww1 * a4[1].x + ww2 * a4[2].x + ww3 * a4[3].x;
        mtv.y += ww0 * a4[0].y + ww1 * a4[1].y + ww2 * a4[2].y + ww3 * a4[3].y;
        mtv.z += ww0 * a4[0].z + ww1 * a4[1].z + ww2 * a4[2].z + ww3 * a4[3].z;
        mtv.w += ww0 * a4[0].w + ww1 * a4[1].w + ww2 * a4[2].w + ww3 * a4[3].w;
        *(float4*)(mt + sl + (size_t)n * DD + d4 * 4) = mtv;

        racc[0].x += e0 * mtv.x; racc[0].y += e0 * mtv.y; racc[0].z += e0 * mtv.z; racc[0].w += e0 * mtv.w;
        racc[1].x += e1 * mtv.x; racc[1].y += e1 * mtv.y; racc[1].z += e1 * mtv.z; racc[1].w += e1 * mtv.w;
        racc[2].x += e2 * mtv.x; racc[2].y += e2 * mtv.y; racc[2].z += e2 * mtv.z; racc[2].w += e2 * mtv.w;
        racc[3].x += e3 * mtv.x; racc[3].y += e3 * mtv.y; racc[3].z += e3 * mtv.z; racc[3].w += e3 * mtv.w;

        m4 = m4n;
    }

    // merge racc across the 4 row-groups within the wave
    #pragma unroll
    for (int off = 16; off < 64; off <<= 1) {
        #pragma unroll
        for (int r = 0; r < 4; r++) {
            racc[r].x += __shfl_xor(racc[r].x, off);
            racc[r].y += __shfl_xor(racc[r].y, off);
            racc[r].z += __shfl_xor(racc[r].z, off);
            racc[r].w += __shfl_xor(racc[r].w, off);
        }
    }
    __syncthreads();   // s_e4 now visible block-wide

    // ---- Z from s_e4 ----
    float z0 = 0.f, z1 = 0.f, z2 = 0.f, z3 = 0.f;
    #pragma unroll
    for (int i = 0; i < 4; i++) {
        const float4 e4 = s_e4[i * 512 + t];
        z0 += e4.x; z1 += e4.y; z2 += e4.z; z3 += e4.w;
    }
    #pragma unroll
    for (int off = 1; off < 64; off <<= 1) {
        z0 += __shfl_xor(z0, off); z1 += __shfl_xor(z1, off);
        z2 += __shfl_xor(z2, off); z3 += __shfl_xor(z3, off);
    }
    if (lane == 0) { lz[wave][0] = z0; lz[wave][1] = z1; lz[wave][2] = z2; lz[wave][3] = z3; }
    __syncthreads();
    float zi[4];
    #pragma unroll
    for (int r = 0; r < 4; r++) {
        float Z = 0.f;
        #pragma unroll
        for (int w = 0; w < 8; w++) Z += lz[w][r];
        zi[r] = 1.0f / Z;
    }

    // ---- phase 2: wr_t and wu_t ----
    {
        float* wro = out + OUT_WR + (size_t)b * (RR * NN);
        float* wuo = out + OUT_WU + (size_t)b * NN;
        #pragma unroll
        for (int i = 0; i < 4; i++) {
            const int n = i * 512 + t;
            const float4 e4 = s_e4[n];
            const float wl = (n == id4[0] || n == id4[1] || n == id4[2] || n == id4[3]) ? 1.0f : 0.0f;
            const float wv0 = e4.x * zi[0], wv1 = e4.y * zi[1], wv2 = e4.z * zi[2], wv3 = e4.w * zi[3];
            wro[0 * NN + n] = wv0; wro[1 * NN + n] = wv1;
            wro[2 * NN + n] = wv2; wro[3 * NN + n] = wv3;
            float acc = wv0 + wv1 + wv2 + wv3;
            acc += fmaf(sa[0], wrp[0 * NN + n] - wl, wl);
            acc += fmaf(sa[1], wrp[1 * NN + n] - wl, wl);
            acc += fmaf(sa[2], wrp[2 * NN + n] - wl, wl);
            acc += fmaf(sa[3], wrp[3 * NN + n] - wl, wl);
            wuo[n] = GAMMA * wuprev[(size_t)b * NN + n] + acc;
        }
    }
    __syncthreads();   // phase-2 reads of s_e4 done; safe to reuse as lr

    // ---- final r_t merge across the 8 waves ----
    float4* lr = s_e4;
    if (row4 == 0) {
        #pragma unroll
        for (int r = 0; r < 4; r++) lr[wave * 64 + r * 16 + d4] = racc[r];
    }
    __syncthreads();
    if (t < 64) {
        const int r = t >> 4, dd = t & 15;
        float4 s = make_float4(0.f, 0.f, 0.f, 0.f);
        #pragma unroll
        for (int w = 0; w < 8; w++) {
            const float4 v = lr[w * 64 + r * 16 + dd];
            s.x += v.x; s.y += v.y; s.z += v.z; s.w += v.w;
        }
        const float inv = zi[r];
        const float4 rt = make_float4(s.x * inv, s.y * inv, s.z * inv, s.w * inv);
        *(float4*)(out + OUT_RT + (size_t)b * 256 + r * 64 + dd * 4) = rt;
        *(float4*)(out + (size_t)b * 768 + 512 + r * 64 + dd * 4) = rt;
    }
}

// ===================== host =====================
extern "C" void kernel_launch(void* const* d_in, const int* in_sizes, int n_in,
                              void* d_out, int out_size, void* d_ws, size_t ws_size,
                              hipStream_t stream)
{
    const float* x      = (const float*)d_in[0];
    const float* Mprev  = (const float*)d_in[1];
    const float* rprev  = (const float*)d_in[2];
    const float* hprev  = (const float*)d_in[3];
    const float* cprev  = (const float*)d_in[4];
    const float* wuprev = (const float*)d_in[5];
    const float* wrprev = (const float*)d_in[6];
    const float* Wih    = (const float*)d_in[7];
    const float* bih    = (const float*)d_in[8];
    const float* Whh    = (const float*)d_in[9];
    const float* bhh    = (const float*)d_in[10];
    const float* Wlin   = (const float*)d_in[11];
    const float* blin   = (const float*)d_in[12];
    float* out = (float*)d_out;

    unsigned* Abf  = (unsigned*)(out + OUT_WU);              // 2 MB   (dead until fused_mem)
    unsigned* Wlbf = Abf + (size_t)1048576;                  // +4 MB offset, 288 KB
    unsigned* Wbf  = (unsigned*)(out + OUT_WR);              // 4 MB   (dead until fused_mem)
    unsigned* Hbf  = (unsigned*)(out + OUT_RT);              // 1 MB   (dead until fused_mem)

    conv_all<<<1665, 256, 0, stream>>>(x, rprev, hprev, Wih, Whh, Wlin, Abf, Wbf, Wlbf);
    gemm_gates<<<dim3(32, 16), 256, 0, stream>>>(Abf, Wbf, bih, bhh, out);
    lstm_pw<<<512, 256, 0, stream>>>(cprev, out);
    gemm_p<<<dim3(9, 16), 256, 0, stream>>>(Hbf, Wlbf, blin, out);
    fused_mem<<<1024, 512, 0, stream>>>(Mprev, wrprev, wuprev, out);
}

// Round 16
// 287.542 us; speedup vs baseline: 1.3184x; 1.3184x over previous
//
#include <hip/hip_runtime.h>
#include <math.h>

// ---- problem constants ----
constexpr int BB   = 1024;   // batch
constexpr int NN   = 2048;   // memory slots
constexpr int DD   = 64;     // memory width
constexpr int RR   = 4;      // read heads
constexpr float GAMMA = 0.95f;

// ---- d_out flat layout (float elements, reference return order) ----
constexpr size_t OUT_OUT = 0;                                   // (B, 768)
constexpr size_t OUT_MT  = OUT_OUT + (size_t)BB * 768;          // (B, N, D)
constexpr size_t OUT_RT  = OUT_MT  + (size_t)BB * NN * DD;      // (B, 256)
constexpr size_t OUT_HT  = OUT_RT  + (size_t)BB * 256;          // (B, 512)
constexpr size_t OUT_CT  = OUT_HT  + (size_t)BB * 512;          // (B, 512)
constexpr size_t OUT_WU  = OUT_CT  + (size_t)BB * 512;          // (B, N)
constexpr size_t OUT_WR  = OUT_WU  + (size_t)BB * NN;           // (B, R*N)

// ---- scratch inside M_t region, per-batch slice (header read before overwrite) ----
constexpr int SLICE   = NN * DD;       // 131072
constexpr int OFF_G   = 8456 + NN;     // gates: 2048
constexpr int OFF_P   = OFF_G + 2048;  // p: 520   (rows 196..204 of M_t; read before loop)

// bf16 operand stashes (dead scratch until overwritten by later kernels):
//   A_bf16   [1024][1024]  (2 MB)   at out+OUT_WU
//   Wlin_bf16 [576][512]  (288 KB)  at out+OUT_WU + 4 MB
//   W_bf16   [2048][1024]  (4 MB)   at out+OUT_WR
//   h_bf16   [1024][512]   (1 MB)   at out+OUT_RT (overwritten by fused_mem r_t)

__device__ __forceinline__ float sigmoidf_(float x) { return 1.0f / (1.0f + __expf(-x)); }

typedef short short8 __attribute__((ext_vector_type(8)));
typedef float f32x4  __attribute__((ext_vector_type(4)));

// pack two f32 into one dword of 2 bf16 (round-to-nearest-even)
__device__ __forceinline__ unsigned bf16pack2(float a, float b) {
    unsigned ua = __float_as_uint(a), ub = __float_as_uint(b);
    ua = (ua + 0x7FFFu + ((ua >> 16) & 1u)) >> 16;
    ub = (ub + 0x7FFFu + ((ub >> 16) & 1u)) >> 16;
    return ua | (ub << 16);
}

// VALU-pipe cross-lane add within each 16-lane row: x + dpp(x).
template<int CTRL>
__device__ __forceinline__ float dpp_add(float x) {
    int y = __builtin_amdgcn_update_dpp(0, __float_as_int(x), CTRL, 0xF, 0xF, false);
    return x + __int_as_float(y);
}
template<int CTRL>
__device__ __forceinline__ void dpp_add5(float& a, float& b, float& c, float& d, float& e) {
    a = dpp_add<CTRL>(a); b = dpp_add<CTRL>(b); c = dpp_add<CTRL>(c);
    d = dpp_add<CTRL>(d); e = dpp_add<CTRL>(e);
}
// quad_perm broadcast within each quad
template<int CTRL>
__device__ __forceinline__ float dpp_bcast(float x) {
    return __int_as_float(__builtin_amdgcn_update_dpp(0, __float_as_int(x), CTRL, 0xF, 0xF, false));
}

// ===================== conv_all: f32 -> bf16 stashes (A, W, Wlin) =====================
__global__ __launch_bounds__(256) void conv_all(
    const float* __restrict__ x, const float* __restrict__ rprev, const float* __restrict__ hprev,
    const float* __restrict__ Wih, const float* __restrict__ Whh, const float* __restrict__ Wlin,
    unsigned* __restrict__ Abf, unsigned* __restrict__ Wbf, unsigned* __restrict__ Wlbf)
{
    const int bid = blockIdx.x;
    if (bid < 512) {
        const int gid = bid * 256 + threadIdx.x;
        const int e0 = gid * 8;
        const int row = e0 >> 10, col = e0 & 1023;
        float4 v0, v1;
        if (col < 256)      { const float* p = x + row * 256 + col;
                              v0 = *(const float4*)p; v1 = *(const float4*)(p + 4); }
        else if (col < 512) { const float* p = rprev + row * 256 + (col - 256);
                              v0 = *(const float4*)p; v1 = *(const float4*)(p + 4); }
        else                { const float* p = hprev + row * 512 + (col - 512);
                              v0 = *(const float4*)p; v1 = *(const float4*)(p + 4); }
        uint4 o;
        o.x = bf16pack2(v0.x, v0.y); o.y = bf16pack2(v0.z, v0.w);
        o.z = bf16pack2(v1.x, v1.y); o.w = bf16pack2(v1.z, v1.w);
        *(uint4*)(Abf + (size_t)row * 512 + (col >> 1)) = o;
    } else if (bid < 1536) {
        const int gid = (bid - 512) * 256 + threadIdx.x;
        const int e0 = gid * 8;
        const int row = e0 >> 10, col = e0 & 1023;
        float4 v0, v1;
        if (col < 512) { const float* p = Wih + (size_t)row * 512 + col;
                         v0 = *(const float4*)p; v1 = *(const float4*)(p + 4); }
        else           { const float* p = Whh + (size_t)row * 512 + (col - 512);
                         v0 = *(const float4*)p; v1 = *(const float4*)(p + 4); }
        uint4 o;
        o.x = bf16pack2(v0.x, v0.y); o.y = bf16pack2(v0.z, v0.w);
        o.z = bf16pack2(v1.x, v1.y); o.w = bf16pack2(v1.z, v1.w);
        *(uint4*)(Wbf + (size_t)row * 512 + (col >> 1)) = o;
    } else {
        const int gid = (bid - 1536) * 256 + threadIdx.x;
        const int e0 = gid * 8;
        const int row = e0 >> 9, col = e0 & 511;
        const float* p = Wlin + (size_t)row * 512 + col;
        const float4 v0 = *(const float4*)p, v1 = *(const float4*)(p + 4);
        uint4 o;
        o.x = bf16pack2(v0.x, v0.y); o.y = bf16pack2(v0.z, v0.w);
        o.z = bf16pack2(v1.x, v1.y); o.w = bf16pack2(v1.z, v1.w);
        *(uint4*)(Wlbf + (size_t)row * 256 + (col >> 1)) = o;
    }
}

// ===================== GEMM 1 (bf16 MFMA): gates = A @ W^T + b =====================
__global__ __launch_bounds__(256) void gemm_gates(
    const unsigned* __restrict__ Abf, const unsigned* __restrict__ Wbf,
    const float* __restrict__ bih, const float* __restrict__ bhh,
    float* __restrict__ out)
{
    __shared__ unsigned As[64][20];   // 64 rows x 40 bf16 (32 data + 8 pad)
    __shared__ unsigned Bs[64][20];
    const int t = threadIdx.x;
    const int wave = t >> 6, lane = t & 63;
    const int row0 = blockIdx.y * 64, col0 = blockIdx.x * 64;
    const int srow = t >> 2;
    const int sk4  = (t & 3) * 4;
    const int wm = wave >> 1, wn = wave & 1;
    const int lrow = lane & 15;
    const int ldw  = (lane >> 4) * 4;

    f32x4 acc00 = {0.f,0.f,0.f,0.f}, acc01 = {0.f,0.f,0.f,0.f};
    f32x4 acc10 = {0.f,0.f,0.f,0.f}, acc11 = {0.f,0.f,0.f,0.f};

    for (int k0 = 0; k0 < 512; k0 += 16) {   // u32 units: 32 bf16 per step
        const uint4 av = *(const uint4*)(Abf + (size_t)(row0 + srow) * 512 + k0 + sk4);
        const uint4 bv = *(const uint4*)(Wbf + (size_t)(col0 + srow) * 512 + k0 + sk4);
        __syncthreads();
        *(uint4*)&As[srow][sk4] = av;
        *(uint4*)&Bs[srow][sk4] = bv;
        __syncthreads();
        const short8 a0 = *(const short8*)&As[32 * wm + lrow][ldw];
        const short8 a1 = *(const short8*)&As[32 * wm + 16 + lrow][ldw];
        const short8 b0 = *(const short8*)&Bs[32 * wn + lrow][ldw];
        const short8 b1 = *(const short8*)&Bs[32 * wn + 16 + lrow][ldw];
        acc00 = __builtin_amdgcn_mfma_f32_16x16x32_bf16(a0, b0, acc00, 0, 0, 0);
        acc01 = __builtin_amdgcn_mfma_f32_16x16x32_bf16(a0, b1, acc01, 0, 0, 0);
        acc10 = __builtin_amdgcn_mfma_f32_16x16x32_bf16(a1, b0, acc10, 0, 0, 0);
        acc11 = __builtin_amdgcn_mfma_f32_16x16x32_bf16(a1, b1, acc11, 0, 0, 0);
    }

    float* mt = out + OUT_MT;
    const int rbase = row0 + 32 * wm + (lane >> 4) * 4;
    #pragma unroll
    for (int ni = 0; ni < 2; ni++) {
        const int col = col0 + 32 * wn + 16 * ni + lrow;
        const float bb = bih[col] + bhh[col];
        #pragma unroll
        for (int reg = 0; reg < 4; reg++) {
            const float v0 = (ni == 0) ? acc00[reg] : acc01[reg];
            const float v1 = (ni == 0) ? acc10[reg] : acc11[reg];
            mt[(size_t)(rbase + reg) * SLICE + OFF_G + col] = v0 + bb;
            mt[(size_t)(rbase + 16 + reg) * SLICE + OFF_G + col] = v1 + bb;
        }
    }
}

// ===================== LSTM pointwise (float4) + h bf16 stash =====================
__global__ __launch_bounds__(256) void lstm_pw(const float* __restrict__ cprev, float* __restrict__ out)
{
    const size_t e0 = ((size_t)blockIdx.x * 256 + threadIdx.x) * 4;  // 0 .. B*512-4
    const int b = (int)(e0 >> 9), j = (int)(e0 & 511);
    const float* g = out + OUT_MT + (size_t)b * SLICE + OFF_G;
    const float4 ig = *(const float4*)(g + j);
    const float4 fg = *(const float4*)(g + 512 + j);
    const float4 gg = *(const float4*)(g + 1024 + j);
    const float4 og = *(const float4*)(g + 1536 + j);
    const float4 cp = *(const float4*)(cprev + e0);
    float4 c, h;
    c.x = sigmoidf_(fg.x) * cp.x + sigmoidf_(ig.x) * tanhf(gg.x);
    c.y = sigmoidf_(fg.y) * cp.y + sigmoidf_(ig.y) * tanhf(gg.y);
    c.z = sigmoidf_(fg.z) * cp.z + sigmoidf_(ig.z) * tanhf(gg.z);
    c.w = sigmoidf_(fg.w) * cp.w + sigmoidf_(ig.w) * tanhf(gg.w);
    h.x = sigmoidf_(og.x) * tanhf(c.x);
    h.y = sigmoidf_(og.y) * tanhf(c.y);
    h.z = sigmoidf_(og.z) * tanhf(c.z);
    h.w = sigmoidf_(og.w) * tanhf(c.w);
    *(float4*)(out + OUT_CT + e0) = c;
    *(float4*)(out + OUT_HT + e0) = h;
    *(float4*)(out + (size_t)b * 768 + j) = h;
    unsigned* hbf = (unsigned*)(out + OUT_RT);
    uint2 hp; hp.x = bf16pack2(h.x, h.y); hp.y = bf16pack2(h.z, h.w);
    *(uint2*)(hbf + (size_t)b * 256 + (j >> 1)) = hp;
}

// ===================== GEMM 2 (bf16 MFMA): p = h @ Wlin^T + b_lin =====================
__global__ __launch_bounds__(256) void gemm_p(
    const unsigned* __restrict__ Hbf, const unsigned* __restrict__ Wlbf,
    const float* __restrict__ blin, float* __restrict__ out)
{
    __shared__ unsigned As[64][20];
    __shared__ unsigned Bs[64][20];
    const int t = threadIdx.x;
    const int wave = t >> 6, lane = t & 63;
    const int row0 = blockIdx.y * 64, col0 = blockIdx.x * 64;
    const int srow = t >> 2;
    const int sk4  = (t & 3) * 4;
    const int wm = wave >> 1, wn = wave & 1;
    const int lrow = lane & 15;
    const int ldw  = (lane >> 4) * 4;

    f32x4 acc00 = {0.f,0.f,0.f,0.f}, acc01 = {0.f,0.f,0.f,0.f};
    f32x4 acc10 = {0.f,0.f,0.f,0.f}, acc11 = {0.f,0.f,0.f,0.f};

    for (int k0 = 0; k0 < 256; k0 += 16) {   // u32 units: K=512 bf16
        const uint4 av = *(const uint4*)(Hbf  + (size_t)(row0 + srow) * 256 + k0 + sk4);
        const uint4 bv = *(const uint4*)(Wlbf + (size_t)(col0 + srow) * 256 + k0 + sk4);
        __syncthreads();
        *(uint4*)&As[srow][sk4] = av;
        *(uint4*)&Bs[srow][sk4] = bv;
        __syncthreads();
        const short8 a0 = *(const short8*)&As[32 * wm + lrow][ldw];
        const short8 a1 = *(const short8*)&As[32 * wm + 16 + lrow][ldw];
        const short8 b0 = *(const short8*)&Bs[32 * wn + lrow][ldw];
        const short8 b1 = *(const short8*)&Bs[32 * wn + 16 + lrow][ldw];
        acc00 = __builtin_amdgcn_mfma_f32_16x16x32_bf16(a0, b0, acc00, 0, 0, 0);
        acc01 = __builtin_amdgcn_mfma_f32_16x16x32_bf16(a0, b1, acc01, 0, 0, 0);
        acc10 = __builtin_amdgcn_mfma_f32_16x16x32_bf16(a1, b0, acc10, 0, 0, 0);
        acc11 = __builtin_amdgcn_mfma_f32_16x16x32_bf16(a1, b1, acc11, 0, 0, 0);
    }

    float* mt = out + OUT_MT;
    const int rbase = row0 + 32 * wm + (lane >> 4) * 4;
    #pragma unroll
    for (int ni = 0; ni < 2; ni++) {
        const int col = col0 + 32 * wn + 16 * ni + lrow;
        if (col < 516) {
            const float bb = blin[col];
            #pragma unroll
            for (int reg = 0; reg < 4; reg++) {
                const float v0 = (ni == 0) ? acc00[reg] : acc01[reg];
                const float v1 = (ni == 0) ? acc10[reg] : acc11[reg];
                mt[(size_t)(rbase + reg) * SLICE + OFF_P + col] = v0 + bb;
                mt[(size_t)(rbase + 16 + reg) * SLICE + OFF_P + col] = v1 + bb;
            }
        }
    }
}

// ===================== FUSED: header (k/a/sa/rck/argmin) + memory pass + softmax ==========
// One block per batch (512 thr = 8 waves). Single M_prev read, single M_t write.
// Row mapping: n = it*32 + wave*4 + row4 (block walks 32 consecutive rows per iter —
// verified-good streaming pattern; round-15's per-group remap scattered it, -92 µs revert).
// Exp dedup: lane q=lane&3 computes exp for head q; quad_perm broadcasts e0..e3.
__global__ __launch_bounds__(512) void fused_mem(
    const float* __restrict__ Mprev, const float* __restrict__ wrprev,
    const float* __restrict__ wuprev, float* __restrict__ out)
{
    const int b = blockIdx.x, t = threadIdx.x;
    const int wave = t >> 6, lane = t & 63;
    const int row4 = lane >> 4, d4 = lane & 15;
    float* mt = out + OUT_MT;
    const size_t sl = (size_t)b * SLICE;

    __shared__ float4 s_e4[NN];     // 32 KB: e[n][r]; reused as lr in final merge
    __shared__ float  lz[8][4];
    __shared__ float  s_k[256], s_a[256];
    __shared__ float  s_sa[4], s_rck[4];
    __shared__ float  wvred[8];
    __shared__ int    wired[8];
    __shared__ int    chosen[4];

    // ---- header part 1: k, a, sigma(alpha), 1/||k|| from p (waves 0-3) ----
    {
        const float* p = mt + sl + OFF_P;
        if (t < 256) {
            const int r = t >> 6, d = t & 63;
            const float kv = tanhf(p[r * 64 + d]);
            const float av = tanhf(p[256 + r * 64 + d]);
            s_k[t] = kv; s_a[t] = av;
            float s2 = kv * kv;
            #pragma unroll
            for (int off = 1; off < 64; off <<= 1) s2 += __shfl_xor(s2, off);
            if (d == 0) s_rck[r] = rsqrtf(s2);
            if (t < 4) s_sa[t] = sigmoidf_(p[512 + t]);
        }
    }

    // ---- header part 2: 4 smallest wu_prev indices (tie -> larger index) ----
    {
        float wu4[4];
        #pragma unroll
        for (int i = 0; i < 4; i++) wu4[i] = wuprev[(size_t)b * NN + t + i * 512];
        for (int it = 0; it < 4; it++) {
            float bv = 3.4e38f; int bi = -1;
            #pragma unroll
            for (int i = 0; i < 4; i++) {
                const int n = t + i * 512;
                bool skip = false;
                for (int j = 0; j < it; j++) skip = skip || (n == chosen[j]);
                const float v = wu4[i];
                if (!skip && (v < bv || (v == bv && n > bi))) { bv = v; bi = n; }
            }
            #pragma unroll
            for (int off = 1; off < 64; off <<= 1) {
                const float v2 = __shfl_xor(bv, off);
                const int   i2 = __shfl_xor(bi, off);
                if (v2 < bv || (v2 == bv && i2 > bi)) { bv = v2; bi = i2; }
            }
            if (lane == 0) { wvred[wave] = bv; wired[wave] = bi; }
            __syncthreads();
            if (t == 0) {
                float fv = wvred[0]; int fi = wired[0];
                #pragma unroll
                for (int w = 1; w < 8; w++) {
                    if (wvred[w] < fv || (wvred[w] == fv && wired[w] > fi)) { fv = wvred[w]; fi = wired[w]; }
                }
                chosen[it] = fi;
            }
            __syncthreads();
        }
    }

    // ---- gather header results ----
    float sa[4], rck[4]; int id4[4];
    float4 k4[4], a4[4];
    #pragma unroll
    for (int r = 0; r < 4; r++) {
        sa[r]  = s_sa[r];
        rck[r] = s_rck[r];
        id4[r] = chosen[r];
        k4[r] = *(const float4*)&s_k[r * 64 + d4 * 4];
        a4[r] = *(const float4*)&s_a[r * 64 + d4 * 4];
    }
    // per-lane rck for the dedup'd exp (static selects, no dynamic indexing)
    const float rck_lane = (lane & 2) ? ((lane & 1) ? rck[3] : rck[2])
                                      : ((lane & 1) ? rck[1] : rck[0]);

    const float* wrp = wrprev + (size_t)b * (RR * NN);
    const int kill = id4[0];
    const size_t mbase = (size_t)b * NN * DD + (size_t)(d4 * 4);

    float4 racc[4];
    #pragma unroll
    for (int r = 0; r < 4; r++) racc[r] = make_float4(0.f, 0.f, 0.f, 0.f);

    // prologue: load first row
    float4 m4 = *(const float4*)(Mprev + mbase + (size_t)(wave * 4 + row4) * DD);

    for (int it = 0; it < 64; it++) {
        const int n = it * 32 + wave * 4 + row4;
        const int nn = (n + 32) & (NN - 1);            // wrapped prefetch (last iter harmless)
        const float4 m4n = *(const float4*)(Mprev + mbase + (size_t)nn * DD);  // prefetch next
        const float w0 = wrp[0 * NN + n];
        const float w1 = wrp[1 * NN + n];
        const float w2 = wrp[2 * NN + n];
        const float w3 = wrp[3 * NN + n];

        float nrm = m4.x * m4.x + m4.y * m4.y + m4.z * m4.z + m4.w * m4.w;
        float ip0 = k4[0].x * m4.x + k4[0].y * m4.y + k4[0].z * m4.z + k4[0].w * m4.w;
        float ip1 = k4[1].x * m4.x + k4[1].y * m4.y + k4[1].z * m4.z + k4[1].w * m4.w;
        float ip2 = k4[2].x * m4.x + k4[2].y * m4.y + k4[2].z * m4.z + k4[2].w * m4.w;
        float ip3 = k4[3].x * m4.x + k4[3].y * m4.y + k4[3].z * m4.z + k4[3].w * m4.w;
        dpp_add5<0xB1>(nrm, ip0, ip1, ip2, ip3);   // quad_perm xor1
        dpp_add5<0x4E>(nrm, ip0, ip1, ip2, ip3);   // quad_perm xor2
        dpp_add5<0x124>(nrm, ip0, ip1, ip2, ip3);  // row_ror:4
        dpp_add5<0x128>(nrm, ip0, ip1, ip2, ip3);  // row_ror:8

        const float rsn = rsqrtf(fmaxf(nrm, 1e-30f));
        // exp dedup: lane q computes head q's exp; quad_perm broadcasts all 4
        const float ipsel = (lane & 2) ? ((lane & 1) ? ip3 : ip2)
                                       : ((lane & 1) ? ip1 : ip0);
        const float esel = __expf(ipsel * rck_lane * rsn);
        const float e0 = dpp_bcast<0x00>(esel);
        const float e1 = dpp_bcast<0x55>(esel);
        const float e2 = dpp_bcast<0xAA>(esel);
        const float e3 = dpp_bcast<0xFF>(esel);
        if (d4 == 0) s_e4[n] = make_float4(e0, e1, e2, e3);

        const float wlu = (n == id4[0] || n == id4[1] || n == id4[2] || n == id4[3]) ? 1.0f : 0.0f;
        float4 mtv = m4;
        if (n == kill) { mtv.x = 0.f; mtv.y = 0.f; mtv.z = 0.f; mtv.w = 0.f; }
        const float ww0 = fmaf(sa[0], w0 - wlu, wlu);
        const float ww1 = fmaf(sa[1], w1 - wlu, wlu);
        const float ww2 = fmaf(sa[2], w2 - wlu, wlu);
        const float ww3 = fmaf(sa[3], w3 - wlu, wlu);
        mtv.x += ww0 * a4[0].x + ww1 * a4[1].x + ww2 * a4[2].x + ww3 * a4[3].x;
        mtv.y += ww0 * a4[0].y + ww1 * a4[1].y + ww2 * a4[2].y + ww3 * a4[3].y;
        mtv.z += ww0 * a4[0].z + ww1 * a4[1].z + ww2 * a4[2].z + ww3 * a4[3].z;
        mtv.w += ww0 * a4[0].w + ww1 * a4[1].w + ww2 * a4[2].w + ww3 * a4[3].w;
        *(float4*)(mt + sl + (size_t)n * DD + d4 * 4) = mtv;

        racc[0].x += e0 * mtv.x; racc[0].y += e0 * mtv.y; racc[0].z += e0 * mtv.z; racc[0].w += e0 * mtv.w;
        racc[1].x += e1 * mtv.x; racc[1].y += e1 * mtv.y; racc[1].z += e1 * mtv.z; racc[1].w += e1 * mtv.w;
        racc[2].x += e2 * mtv.x; racc[2].y += e2 * mtv.y; racc[2].z += e2 * mtv.z; racc[2].w += e2 * mtv.w;
        racc[3].x += e3 * mtv.x; racc[3].y += e3 * mtv.y; racc[3].z += e3 * mtv.z; racc[3].w += e3 * mtv.w;

        m4 = m4n;
    }

    // merge racc across the 4 row-groups within the wave
    #pragma unroll
    for (int off = 16; off < 64; off <<= 1) {
        #pragma unroll
        for (int r = 0; r < 4; r++) {
            racc[r].x += __shfl_xor(racc[r].x, off);
            racc[r].y += __shfl_xor(racc[r].y, off);
            racc[r].z += __shfl_xor(racc[r].z, off);
            racc[r].w += __shfl_xor(racc[r].w, off);
        }
    }
    __syncthreads();   // s_e4 now visible block-wide

    // ---- Z from s_e4 ----
    float z0 = 0.f, z1 = 0.f, z2 = 0.f, z3 = 0.f;
    #pragma unroll
    for (int i = 0; i < 4; i++) {
        const float4 e4 = s_e4[i * 512 + t];
        z0 += e4.x; z1 += e4.y; z2 += e4.z; z3 += e4.w;
    }
    #pragma unroll
    for (int off = 1; off < 64; off <<= 1) {
        z0 += __shfl_xor(z0, off); z1 += __shfl_xor(z1, off);
        z2 += __shfl_xor(z2, off); z3 += __shfl_xor(z3, off);
    }
    if (lane == 0) { lz[wave][0] = z0; lz[wave][1] = z1; lz[wave][2] = z2; lz[wave][3] = z3; }
    __syncthreads();
    float zi[4];
    #pragma unroll
    for (int r = 0; r < 4; r++) {
        float Z = 0.f;
        #pragma unroll
        for (int w = 0; w < 8; w++) Z += lz[w][r];
        zi[r] = 1.0f / Z;
    }

    // ---- phase 2: wr_t and wu_t ----
    {
        float* wro = out + OUT_WR + (size_t)b * (RR * NN);
        float* wuo = out + OUT_WU + (size_t)b * NN;
        #pragma unroll
        for (int i = 0; i < 4; i++) {
            const int n = i * 512 + t;
            const float4 e4 = s_e4[n];
            const float wl = (n == id4[0] || n == id4[1] || n == id4[2] || n == id4[3]) ? 1.0f : 0.0f;
            const float wv0 = e4.x * zi[0], wv1 = e4.y * zi[1], wv2 = e4.z * zi[2], wv3 = e4.w * zi[3];
            wro[0 * NN + n] = wv0; wro[1 * NN + n] = wv1;
            wro[2 * NN + n] = wv2; wro[3 * NN + n] = wv3;
            float acc = wv0 + wv1 + wv2 + wv3;
            acc += fmaf(sa[0], wrp[0 * NN + n] - wl, wl);
            acc += fmaf(sa[1], wrp[1 * NN + n] - wl, wl);
            acc += fmaf(sa[2], wrp[2 * NN + n] - wl, wl);
            acc += fmaf(sa[3], wrp[3 * NN + n] - wl, wl);
            wuo[n] = GAMMA * wuprev[(size_t)b * NN + n] + acc;
        }
    }
    __syncthreads();   // phase-2 reads of s_e4 done; safe to reuse as lr

    // ---- final r_t merge across the 8 waves ----
    float4* lr = s_e4;
    if (row4 == 0) {
        #pragma unroll
        for (int r = 0; r < 4; r++) lr[wave * 64 + r * 16 + d4] = racc[r];
    }
    __syncthreads();
    if (t < 64) {
        const int r = t >> 4, dd = t & 15;
        float4 s = make_float4(0.f, 0.f, 0.f, 0.f);
        #pragma unroll
        for (int w = 0; w < 8; w++) {
            const float4 v = lr[w * 64 + r * 16 + dd];
            s.x += v.x; s.y += v.y; s.z += v.z; s.w += v.w;
        }
        const float inv = zi[r];
        const float4 rt = make_float4(s.x * inv, s.y * inv, s.z * inv, s.w * inv);
        *(float4*)(out + OUT_RT + (size_t)b * 256 + r * 64 + dd * 4) = rt;
        *(float4*)(out + (size_t)b * 768 + 512 + r * 64 + dd * 4) = rt;
    }
}

// ===================== host =====================
extern "C" void kernel_launch(void* const* d_in, const int* in_sizes, int n_in,
                              void* d_out, int out_size, void* d_ws, size_t ws_size,
                              hipStream_t stream)
{
    const float* x      = (const float*)d_in[0];
    const float* Mprev  = (const float*)d_in[1];
    const float* rprev  = (const float*)d_in[2];
    const float* hprev  = (const float*)d_in[3];
    const float* cprev  = (const float*)d_in[4];
    const float* wuprev = (const float*)d_in[5];
    const float* wrprev = (const float*)d_in[6];
    const float* Wih    = (const float*)d_in[7];
    const float* bih    = (const float*)d_in[8];
    const float* Whh    = (const float*)d_in[9];
    const float* bhh    = (const float*)d_in[10];
    const float* Wlin   = (const float*)d_in[11];
    const float* blin   = (const float*)d_in[12];
    float* out = (float*)d_out;

    unsigned* Abf  = (unsigned*)(out + OUT_WU);              // 2 MB   (dead until fused_mem)
    unsigned* Wlbf = Abf + (size_t)1048576;                  // +4 MB offset, 288 KB
    unsigned* Wbf  = (unsigned*)(out + OUT_WR);              // 4 MB   (dead until fused_mem)
    unsigned* Hbf  = (unsigned*)(out + OUT_RT);              // 1 MB   (dead until fused_mem)

    conv_all<<<1665, 256, 0, stream>>>(x, rprev, hprev, Wih, Whh, Wlin, Abf, Wbf, Wlbf);
    gemm_gates<<<dim3(32, 16), 256, 0, stream>>>(Abf, Wbf, bih, bhh, out);
    lstm_pw<<<512, 256, 0, stream>>>(cprev, out);
    gemm_p<<<dim3(9, 16), 256, 0, stream>>>(Hbf, Wlbf, blin, out);
    fused_mem<<<1024, 512, 0, stream>>>(Mprev, wrprev, wuprev, out);
}